// Round 10
// baseline (110.271 us; speedup 1.0000x reference)
//
#include <hip/hip_runtime.h>
#include <math.h>

#define NPOS 110592

typedef float f32x4 __attribute__((ext_vector_type(4)));
typedef short bf16x8 __attribute__((ext_vector_type(8)));
typedef unsigned u32;
typedef u32 u32x2 __attribute__((ext_vector_type(2)));
typedef u32 u32x4 __attribute__((ext_vector_type(4)));

#define MFMA __builtin_amdgcn_mfma_f32_16x16x32_bf16

__device__ __forceinline__ short f2bf(float f) {
    u32 u = __builtin_bit_cast(u32, f);
    u += 0x7fffu + ((u >> 16) & 1u);
    return (short)(u >> 16);
}
// ALU round-to-nearest-even pack (proven rounds 1-9). Do NOT swap for inline-asm
// cvt_pk without an isolated A/B — round 7's NaN regression had it as a suspect.
__device__ __forceinline__ u32 pack2(float a, float b) {
    return (u32)(unsigned short)f2bf(a) | ((u32)(unsigned short)f2bf(b) << 16);
}

union FragU { u32 w[4]; bf16x8 v; };
// C-layout regs (k on slots g*8+{0,1,2,3}) -> K-padded fragment, slots 4..7 = 0.
__device__ __forceinline__ bf16x8 padfrag(u32 a, u32 b) {
    FragU f; f.w[0] = a; f.w[1] = b; f.w[2] = 0u; f.w[3] = 0u; return f.v;
}

// ---- prep: bf16 weights, g_in folded into w_qkv columns ----
__global__ __launch_bounds__(256) void la_prep(const float* __restrict__ wqkv,
                                               const float* __restrict__ g_in,
                                               const float* __restrict__ wout,
                                               short* __restrict__ wqkv_bf,
                                               short* __restrict__ wout_bf)
{
    int i = blockIdx.x * 256 + threadIdx.x;
    if (i < 24576) wqkv_bf[i] = f2bf(wqkv[i] * g_in[i & 63]);
    if (i < 8192)  wout_bf[i] = f2bf(wout[i]);
}

// ---- p01: fused pass0+pass1 (round-9 structure; xnT write-back moved after compute
//      so phase-B MFMA work starts immediately after the staging barrier). ----
__global__ __launch_bounds__(256, 3) void la_p01(
    const float* __restrict__ x, const short* __restrict__ wkv,
    short* __restrict__ xnT, float* __restrict__ partials)
{
    __shared__ __align__(16) char smem[34816];
    char* xnz = smem;                                              // 32768 B, phase A/B
    float (*lctx)[2][32][33] = (float (*)[2][32][33])smem;         // 33792 B, phase C
    float (*lz)[2][32]       = (float (*)[2][32])(smem + 33792);   //  1024 B, phase C

    const int tid = threadIdx.x, lane = tid & 63, wid = tid >> 6;
    const int g = lane >> 4, m = lane & 15;
    const int blk = blockIdx.x;
    const int batch = blk / 432;
    const int pb = (blk % 432) * 256;

    // A1. coalesced x read + in-thread rmsnorm
    const float* base = x + (size_t)batch * 64 * NPOS + pb + tid;
    float xv[64]; float ss = 0.f;
#pragma unroll
    for (int c = 0; c < 64; ++c) { float t = base[(size_t)c * NPOS]; xv[c] = t; ss += t * t; }
    float rn = 8.0f / fmaxf(sqrtf(ss), 1e-12f);

    // A2. stage bf16 row, 16B chunks XOR-swizzled
    char* row = xnz + tid * 128;
#pragma unroll
    for (int ch = 0; ch < 8; ++ch) {
        u32x4 w;
        w.x = pack2(xv[ch*8+0] * rn, xv[ch*8+1] * rn);
        w.y = pack2(xv[ch*8+2] * rn, xv[ch*8+3] * rn);
        w.z = pack2(xv[ch*8+4] * rn, xv[ch*8+5] * rn);
        w.w = pack2(xv[ch*8+6] * rn, xv[ch*8+7] * rn);
        *(u32x4*)(row + ((ch ^ (tid & 7)) << 4)) = w;
    }
    __syncthreads();

    // B. compute: wave wid -> chunk group cg (128 pos), head pair hbase.
    const int cg = wid >> 1, hbase = (wid & 1) * 2;

    // Hoisted weight fragments (static indices; loaded once per wave, not per ic)
    bf16x8 wkA[2][2][2], wvA[2][2][2];   // [hh][tile][half]
#pragma unroll
    for (int hh = 0; hh < 2; ++hh) {
#pragma unroll
        for (int dt = 0; dt < 2; ++dt) {
            const short* wr = wkv + (size_t)(128 + (hbase + hh) * 32 + dt * 16 + m) * 64 + g * 8;
            wkA[hh][dt][0] = *(const bf16x8*)wr;
            wkA[hh][dt][1] = *(const bf16x8*)(wr + 32);
        }
#pragma unroll
        for (int et = 0; et < 2; ++et) {
            const short* wr = wkv + (size_t)(256 + (hbase + hh) * 32 + et * 16 + m) * 64 + g * 8;
            wvA[hh][et][0] = *(const bf16x8*)wr;
            wvA[hh][et][1] = *(const bf16x8*)(wr + 32);
        }
    }

    f32x4 acc[2][2][2];   // [hh][dt][et] - all static indices
#pragma unroll
    for (int hh = 0; hh < 2; ++hh)
#pragma unroll
        for (int dt = 0; dt < 2; ++dt)
#pragma unroll
            for (int et = 0; et < 2; ++et) acc[hh][dt][et] = (f32x4){0.f, 0.f, 0.f, 0.f};
    float zacc[2][2] = {{0.f, 0.f}, {0.f, 0.f}};

#pragma unroll 1
    for (int ic = 0; ic < 4; ++ic) {
        bf16x8 af[2][2];
#pragma unroll
        for (int mt = 0; mt < 2; ++mt)
#pragma unroll
            for (int kf = 0; kf < 2; ++kf) {
                int rowi = cg * 128 + ic * 32 + mt * 16 + m;
                af[mt][kf] = *(const bf16x8*)(xnz + rowi * 128 + (((kf*4+g) ^ (rowi & 7)) << 4));
            }
#pragma unroll
        for (int hh = 0; hh < 2; ++hh) {
            u32 ek[2][2][2], vv[2][2][2];
#pragma unroll
            for (int dt = 0; dt < 2; ++dt) {
#pragma unroll
                for (int mt = 0; mt < 2; ++mt) {
                    f32x4 a = {0.f, 0.f, 0.f, 0.f};
                    a = MFMA(af[mt][0], wkA[hh][dt][0], a, 0, 0, 0);
                    a = MFMA(af[mt][1], wkA[hh][dt][1], a, 0, 0, 0);
                    float e0 = __expf(a[0]), e1 = __expf(a[1]);
                    float e2 = __expf(a[2]), e3 = __expf(a[3]);
                    zacc[hh][dt] += (e0 + e1) + (e2 + e3);
                    ek[dt][mt][0] = pack2(e0, e1);
                    ek[dt][mt][1] = pack2(e2, e3);
                }
            }
#pragma unroll
            for (int et = 0; et < 2; ++et) {
#pragma unroll
                for (int mt = 0; mt < 2; ++mt) {
                    f32x4 a = {0.f, 0.f, 0.f, 0.f};
                    a = MFMA(af[mt][0], wvA[hh][et][0], a, 0, 0, 0);
                    a = MFMA(af[mt][1], wvA[hh][et][1], a, 0, 0, 0);
                    vv[et][mt][0] = pack2(a[0], a[1]);
                    vv[et][mt][1] = pack2(a[2], a[3]);
                }
            }
#pragma unroll
            for (int dt = 0; dt < 2; ++dt)
#pragma unroll
                for (int et = 0; et < 2; ++et)
#pragma unroll
                    for (int mt = 0; mt < 2; ++mt)
                        acc[hh][dt][et] = MFMA(padfrag(ek[dt][mt][0], ek[dt][mt][1]),
                                               padfrag(vv[et][mt][0], vv[et][mt][1]),
                                               acc[hh][dt][et], 0, 0, 0);
        }
    }

    // A3 (moved): coalesced xnT write for pass2. xnz still intact; stores drain
    // in the shadow of other blocks' compute.
    char* dst = (char*)xnT + ((size_t)batch * NPOS + pb) * 128;
#pragma unroll
    for (int i = 0; i < 8; ++i) {
        int u = i * 256 + tid;
        int r = u >> 3, cl = u & 7;
        u32x4 w = *(const u32x4*)(xnz + r * 128 + ((cl ^ (r & 7)) << 4));
        *(u32x4*)(dst + (size_t)u * 16) = w;
    }

    // C. combine (unchanged)
    __syncthreads();
#pragma unroll
    for (int hh = 0; hh < 2; ++hh) {
#pragma unroll
        for (int dt = 0; dt < 2; ++dt) {
#pragma unroll
            for (int et = 0; et < 2; ++et)
#pragma unroll
                for (int r4 = 0; r4 < 4; ++r4)
                    lctx[wid][hh][dt * 16 + g * 4 + r4][et * 16 + m] = acc[hh][dt][et][r4];
            float z = zacc[hh][dt];
            z += __shfl_xor(z, 16);
            z += __shfl_xor(z, 32);
            if (g == 0) lz[wid][hh][dt * 16 + m] = z;
        }
    }
    __syncthreads();

    float* P = partials + (size_t)blk * 4224;
    for (int i = tid; i < 4096; i += 256) {
        int h = i >> 10, de = i & 1023, d = de >> 5, e = de & 31;
        int w0 = h >> 1, hh2 = h & 1;
        P[i] = lctx[w0][hh2][d][e] + lctx[w0 + 2][hh2][d][e];
    }
    if (tid < 128) {
        int h = tid >> 5, d = tid & 31;
        P[4096 + tid] = lz[h >> 1][h & 1][d] + lz[(h >> 1) + 2][h & 1][d];
    }
}

// ---- ctxt stage A: reduce 432 partials/batch -> 16 groups of 27 ----
__global__ __launch_bounds__(256) void la_ctxt_a(const float* __restrict__ partials,
                                                 float* __restrict__ part2)
{
    int t = blockIdx.x * 256 + threadIdx.x;       // 2*16*4224 = 135168 exactly
    int b = t / 67584;
    int rem = t % 67584;
    int grp = rem / 4224;
    int i = rem % 4224;
    const float* P = partials + ((size_t)(b * 432 + grp * 27)) * 4224 + i;
    float s = 0.f;
#pragma unroll 3
    for (int j = 0; j < 27; ++j) s += P[(size_t)j * 4224];
    part2[((size_t)(b * 16 + grp)) * 4224 + i] = s;
}

// ---- ctxt stage B: one block per (b,h): final sum + mem_kv fold + emit ctxA frags ----
__global__ __launch_bounds__(256) void la_ctxt_b(const float* __restrict__ part2,
                                                 const float* __restrict__ mem_kv,
                                                 u32* __restrict__ ctxA)
{
    __shared__ float ctxN[32][33];
    const int tid = threadIdx.x;
    const int b = blockIdx.x >> 2, h = blockIdx.x & 3;
    const float* P = part2 + (size_t)b * 16 * 4224;
#pragma unroll
    for (int u = 0; u < 4; ++u) {
        int de = tid * 4 + u;
        int d = de >> 5, e = de & 31;
        float S = 0.f, Z = 0.f;
#pragma unroll 4
        for (int grp = 0; grp < 16; ++grp) {
            S += P[(size_t)grp * 4224 + h * 1024 + de];
            Z += P[(size_t)grp * 4224 + 4096 + h * 32 + d];
        }
        const float* mk = mem_kv + (h * 32 + d) * 4;
        const float* mv = mem_kv + 512 + (h * 32 + e) * 4;
#pragma unroll
        for (int mm = 0; mm < 4; ++mm) {
            float ekv = __expf(mk[mm]);
            S += ekv * mv[mm];
            Z += ekv;
        }
        ctxN[d][e] = S / Z;
    }
    __syncthreads();
    // emit A-frag layout: ctxA[(b*4+h)*512 + et*256 + dt*128 + lane*2 + q]
#pragma unroll
    for (int k = 0; k < 2; ++k) {
        int j = tid * 2 + k;                  // 0..511
        int q = j & 1, lanej = (j >> 1) & 63, dt = (j >> 7) & 1, et = (j >> 8) & 1;
        int gg = lanej >> 4, mm = lanej & 15;
        int d0 = dt * 16 + gg * 4 + 2 * q, e = et * 16 + mm;
        ctxA[(size_t)(b * 4 + h) * 512 + j] = pack2(ctxN[d0][e], ctxN[d0 + 1][e]);
    }
}

// ---- pass2: round-9 structure + heads unrolled x2 (round-6-proven) for cross-head
//      ILP: head h+1's loads/MFMA overlap head h's exp->pack->MFMA tail. ----
__global__ __launch_bounds__(256, 3) void la_pass2(
    const short* __restrict__ xnT, const short* __restrict__ wq,
    const u32* __restrict__ ctxA, const short* __restrict__ wout,
    const float* __restrict__ b_out, const float* __restrict__ g_out,
    float* __restrict__ out)
{
    const int tid = threadIdx.x, lane = tid & 63, wid = tid >> 6;
    const int g = lane >> 4, m = lane & 15;
    const int blk = blockIdx.x;
    const int batch = blk / 432;
    const int task = (blk % 432) * 4 + wid;   // [0, 1728): 64-pos tasks per batch
    const int posbase = task * 64;

    const short* xp = xnT + ((size_t)batch * NPOS + posbase) * 64;
    bf16x8 af[4][2];
#pragma unroll
    for (int mt = 0; mt < 4; ++mt)
#pragma unroll
        for (int kf = 0; kf < 2; ++kf)
            af[mt][kf] = *(const bf16x8*)(xp + (mt * 16 + m) * 64 + kf * 32 + g * 8);

    f32x4 oacc[4][4];   // [ct][mt]
#pragma unroll
    for (int ct = 0; ct < 4; ++ct)
#pragma unroll
        for (int mt = 0; mt < 4; ++mt) oacc[ct][mt] = (f32x4){0.f, 0.f, 0.f, 0.f};

    const float scale = 0.17677669529663687f;   // 32^-0.5
    const u32* cab = ctxA + (size_t)batch * 4 * 512;

#pragma unroll 2
    for (int h = 0; h < 4; ++h) {
        // EQ = exp(Wq . Xn^T): C[d][p], d on (g,r), p on m
        u32 eqB[2][4][2];   // [dt][mt][q]
        float dpart[4] = {0.f, 0.f, 0.f, 0.f};
#pragma unroll
        for (int dt = 0; dt < 2; ++dt) {
            const short* wr = wq + (size_t)(h * 32 + dt * 16 + m) * 64 + g * 8;
            bf16x8 a0 = *(const bf16x8*)wr;
            bf16x8 a1 = *(const bf16x8*)(wr + 32);
#pragma unroll
            for (int mt = 0; mt < 4; ++mt) {
                f32x4 a = {0.f, 0.f, 0.f, 0.f};
                a = MFMA(a0, af[mt][0], a, 0, 0, 0);
                a = MFMA(a1, af[mt][1], a, 0, 0, 0);
                float e0 = __expf(a[0]), e1 = __expf(a[1]);
                float e2 = __expf(a[2]), e3 = __expf(a[3]);
                dpart[mt] += (e0 + e1) + (e2 + e3);
                eqB[dt][mt][0] = pack2(e0, e1);
                eqB[dt][mt][1] = pack2(e2, e3);
            }
        }
        float inv[4];
#pragma unroll
        for (int mt = 0; mt < 4; ++mt) {
            float dn = dpart[mt];
            dn += __shfl_xor(dn, 16);
            dn += __shfl_xor(dn, 32);
            inv[mt] = scale / dn;
        }
        // hid[e][p] = sum_d ctx[d][e]*EQ[d][p] (contract d = C-row of EQ)
        u32 hidB[2][4][2];  // [et][mt][q]
#pragma unroll
        for (int et = 0; et < 2; ++et) {
            u32x2 c0 = *(const u32x2*)(cab + h * 512 + et * 256 + 0 * 128 + lane * 2);
            u32x2 c1 = *(const u32x2*)(cab + h * 512 + et * 256 + 1 * 128 + lane * 2);
#pragma unroll
            for (int mt = 0; mt < 4; ++mt) {
                f32x4 hh2 = {0.f, 0.f, 0.f, 0.f};
                hh2 = MFMA(padfrag(c0.x, c0.y), padfrag(eqB[0][mt][0], eqB[0][mt][1]), hh2, 0, 0, 0);
                hh2 = MFMA(padfrag(c1.x, c1.y), padfrag(eqB[1][mt][0], eqB[1][mt][1]), hh2, 0, 0, 0);
                hidB[et][mt][0] = pack2(hh2[0] * inv[mt], hh2[1] * inv[mt]);
                hidB[et][mt][1] = pack2(hh2[2] * inv[mt], hh2[3] * inv[mt]);
            }
        }
        // out[c][p] += sum_e wout[c][e]*hid[e][p] (contract e = C-row of hid)
#pragma unroll
        for (int ct = 0; ct < 4; ++ct)
#pragma unroll
            for (int et = 0; et < 2; ++et) {
                u32x2 wv = *(const u32x2*)(wout + (size_t)(ct * 16 + m) * 128
                                           + h * 32 + et * 16 + g * 4);
                bf16x8 wfr = padfrag(wv.x, wv.y);
#pragma unroll
                for (int mt = 0; mt < 4; ++mt)
                    oacc[ct][mt] = MFMA(wfr, padfrag(hidB[et][mt][0], hidB[et][mt][1]),
                                        oacc[ct][mt], 0, 0, 0);
            }
    }

    // epilogue: +b_out, rmsnorm over c, *g_out, store (c = ct*16+g*4+r, p = posbase+mt*16+m)
    float bo[4][4], go[4][4];
#pragma unroll
    for (int ct = 0; ct < 4; ++ct)
#pragma unroll
        for (int r = 0; r < 4; ++r) {
            int c = ct * 16 + g * 4 + r;
            bo[ct][r] = b_out[c];
            go[ct][r] = g_out[c];
        }
    float* ob = out + (size_t)batch * 64 * NPOS;
#pragma unroll
    for (int mt = 0; mt < 4; ++mt) {
        float vv[4][4]; float s2 = 0.f;
#pragma unroll
        for (int ct = 0; ct < 4; ++ct)
#pragma unroll
            for (int r = 0; r < 4; ++r) {
                float v = oacc[ct][mt][r] + bo[ct][r];
                vv[ct][r] = v;
                s2 += v * v;
            }
        s2 += __shfl_xor(s2, 16);
        s2 += __shfl_xor(s2, 32);
        float rn2 = 8.0f / fmaxf(sqrtf(s2), 1e-12f);
        int pn = posbase + mt * 16 + m;
#pragma unroll
        for (int ct = 0; ct < 4; ++ct)
#pragma unroll
            for (int r = 0; r < 4; ++r)
                ob[(size_t)(ct * 16 + g * 4 + r) * NPOS + pn] = vv[ct][r] * rn2 * go[ct][r];
    }
}

extern "C" void kernel_launch(void* const* d_in, const int* in_sizes, int n_in,
                              void* d_out, int out_size, void* d_ws, size_t ws_size,
                              hipStream_t stream) {
    const float* x      = (const float*)d_in[0];
    const float* g_in   = (const float*)d_in[1];
    const float* w_qkv  = (const float*)d_in[2];
    const float* mem_kv = (const float*)d_in[3];
    const float* w_out  = (const float*)d_in[4];
    const float* b_out  = (const float*)d_in[5];
    const float* g_out  = (const float*)d_in[6];
    float* out = (float*)d_out;

    char* ws = (char*)d_ws;
    short* xnT     = (short*)(ws);                 // 28,311,552 B
    float* part2   = (float*)(ws + 28311552);      //    540,672 B (2*16*4224 f32)
    short* wqkv_bf = (short*)(ws + 28852224);      //     49,152 B
    short* wout_bf = (short*)(ws + 28901376);      //     16,384 B
    u32*   ctxA    = (u32*)  (ws + 28917760);      //     16,384 B (end ~28.9 MB)

    // p01 partials (864*4224 f32 = 14.6 MB) live in d_out scratch; fully consumed
    // by la_ctxt_a before la_pass2 overwrites d_out with the real output.
    float* partials = (float*)d_out;

    la_prep<<<96, 256, 0, stream>>>(w_qkv, g_in, w_out, wqkv_bf, wout_bf);
    la_p01<<<864, 256, 0, stream>>>(x, wqkv_bf, xnT, partials);
    la_ctxt_a<<<528, 256, 0, stream>>>(partials, part2);
    la_ctxt_b<<<8, 256, 0, stream>>>(part2, mem_kv, ctxA);
    la_pass2<<<864, 256, 0, stream>>>(xnT, wqkv_bf, ctxA, wout_bf, b_out, g_out, out);
}

// Round 11
// 98.018 us; speedup vs baseline: 1.1250x; 1.1250x over previous
//
#include <hip/hip_runtime.h>
#include <math.h>

#define NPOS 110592

typedef float f32x4 __attribute__((ext_vector_type(4)));
typedef short bf16x8 __attribute__((ext_vector_type(8)));
typedef unsigned u32;
typedef u32 u32x2 __attribute__((ext_vector_type(2)));
typedef u32 u32x4 __attribute__((ext_vector_type(4)));

#define MFMA __builtin_amdgcn_mfma_f32_16x16x32_bf16

__device__ __forceinline__ short f2bf(float f) {
    u32 u = __builtin_bit_cast(u32, f);
    u += 0x7fffu + ((u >> 16) & 1u);
    return (short)(u >> 16);
}
// ALU round-to-nearest-even pack (proven rounds 1-10).
__device__ __forceinline__ u32 pack2(float a, float b) {
    return (u32)(unsigned short)f2bf(a) | ((u32)(unsigned short)f2bf(b) << 16);
}

union FragU { u32 w[4]; bf16x8 v; };
// C-layout regs (k on slots g*8+{0,1,2,3}) -> K-padded fragment, slots 4..7 = 0.
__device__ __forceinline__ bf16x8 padfrag(u32 a, u32 b) {
    FragU f; f.w[0] = a; f.w[1] = b; f.w[2] = 0u; f.w[3] = 0u; return f.v;
}

// ---- prep: bf16 qkv weights, g_in folded into columns ----
__global__ __launch_bounds__(256) void la_prep(const float* __restrict__ wqkv,
                                               const float* __restrict__ g_in,
                                               short* __restrict__ wqkv_bf)
{
    int i = blockIdx.x * 256 + threadIdx.x;
    if (i < 24576) wqkv_bf[i] = f2bf(wqkv[i] * g_in[i & 63]);
}

// ---- p01: fused pass0+pass1 (round-10 version; proven) ----
__global__ __launch_bounds__(256, 3) void la_p01(
    const float* __restrict__ x, const short* __restrict__ wkv,
    short* __restrict__ xnT, float* __restrict__ partials)
{
    __shared__ __align__(16) char smem[34816];
    char* xnz = smem;                                              // 32768 B, phase A/B
    float (*lctx)[2][32][33] = (float (*)[2][32][33])smem;         // 33792 B, phase C
    float (*lz)[2][32]       = (float (*)[2][32])(smem + 33792);   //  1024 B, phase C

    const int tid = threadIdx.x, lane = tid & 63, wid = tid >> 6;
    const int g = lane >> 4, m = lane & 15;
    const int blk = blockIdx.x;
    const int batch = blk / 432;
    const int pb = (blk % 432) * 256;

    // A1. coalesced x read + in-thread rmsnorm
    const float* base = x + (size_t)batch * 64 * NPOS + pb + tid;
    float xv[64]; float ss = 0.f;
#pragma unroll
    for (int c = 0; c < 64; ++c) { float t = base[(size_t)c * NPOS]; xv[c] = t; ss += t * t; }
    float rn = 8.0f / fmaxf(sqrtf(ss), 1e-12f);

    // A2. stage bf16 row, 16B chunks XOR-swizzled
    char* row = xnz + tid * 128;
#pragma unroll
    for (int ch = 0; ch < 8; ++ch) {
        u32x4 w;
        w.x = pack2(xv[ch*8+0] * rn, xv[ch*8+1] * rn);
        w.y = pack2(xv[ch*8+2] * rn, xv[ch*8+3] * rn);
        w.z = pack2(xv[ch*8+4] * rn, xv[ch*8+5] * rn);
        w.w = pack2(xv[ch*8+6] * rn, xv[ch*8+7] * rn);
        *(u32x4*)(row + ((ch ^ (tid & 7)) << 4)) = w;
    }
    __syncthreads();

    // B. compute: wave wid -> chunk group cg (128 pos), head pair hbase.
    const int cg = wid >> 1, hbase = (wid & 1) * 2;

    bf16x8 wkA[2][2][2], wvA[2][2][2];   // [hh][tile][half], hoisted
#pragma unroll
    for (int hh = 0; hh < 2; ++hh) {
#pragma unroll
        for (int dt = 0; dt < 2; ++dt) {
            const short* wr = wkv + (size_t)(128 + (hbase + hh) * 32 + dt * 16 + m) * 64 + g * 8;
            wkA[hh][dt][0] = *(const bf16x8*)wr;
            wkA[hh][dt][1] = *(const bf16x8*)(wr + 32);
        }
#pragma unroll
        for (int et = 0; et < 2; ++et) {
            const short* wr = wkv + (size_t)(256 + (hbase + hh) * 32 + et * 16 + m) * 64 + g * 8;
            wvA[hh][et][0] = *(const bf16x8*)wr;
            wvA[hh][et][1] = *(const bf16x8*)(wr + 32);
        }
    }

    f32x4 acc[2][2][2];   // [hh][dt][et] - all static indices
#pragma unroll
    for (int hh = 0; hh < 2; ++hh)
#pragma unroll
        for (int dt = 0; dt < 2; ++dt)
#pragma unroll
            for (int et = 0; et < 2; ++et) acc[hh][dt][et] = (f32x4){0.f, 0.f, 0.f, 0.f};
    float zacc[2][2] = {{0.f, 0.f}, {0.f, 0.f}};

#pragma unroll 1
    for (int ic = 0; ic < 4; ++ic) {
        bf16x8 af[2][2];
#pragma unroll
        for (int mt = 0; mt < 2; ++mt)
#pragma unroll
            for (int kf = 0; kf < 2; ++kf) {
                int rowi = cg * 128 + ic * 32 + mt * 16 + m;
                af[mt][kf] = *(const bf16x8*)(xnz + rowi * 128 + (((kf*4+g) ^ (rowi & 7)) << 4));
            }
#pragma unroll
        for (int hh = 0; hh < 2; ++hh) {
            u32 ek[2][2][2], vv[2][2][2];
#pragma unroll
            for (int dt = 0; dt < 2; ++dt) {
#pragma unroll
                for (int mt = 0; mt < 2; ++mt) {
                    f32x4 a = {0.f, 0.f, 0.f, 0.f};
                    a = MFMA(af[mt][0], wkA[hh][dt][0], a, 0, 0, 0);
                    a = MFMA(af[mt][1], wkA[hh][dt][1], a, 0, 0, 0);
                    float e0 = __expf(a[0]), e1 = __expf(a[1]);
                    float e2 = __expf(a[2]), e3 = __expf(a[3]);
                    zacc[hh][dt] += (e0 + e1) + (e2 + e3);
                    ek[dt][mt][0] = pack2(e0, e1);
                    ek[dt][mt][1] = pack2(e2, e3);
                }
            }
#pragma unroll
            for (int et = 0; et < 2; ++et) {
#pragma unroll
                for (int mt = 0; mt < 2; ++mt) {
                    f32x4 a = {0.f, 0.f, 0.f, 0.f};
                    a = MFMA(af[mt][0], wvA[hh][et][0], a, 0, 0, 0);
                    a = MFMA(af[mt][1], wvA[hh][et][1], a, 0, 0, 0);
                    vv[et][mt][0] = pack2(a[0], a[1]);
                    vv[et][mt][1] = pack2(a[2], a[3]);
                }
            }
#pragma unroll
            for (int dt = 0; dt < 2; ++dt)
#pragma unroll
                for (int et = 0; et < 2; ++et)
#pragma unroll
                    for (int mt = 0; mt < 2; ++mt)
                        acc[hh][dt][et] = MFMA(padfrag(ek[dt][mt][0], ek[dt][mt][1]),
                                               padfrag(vv[et][mt][0], vv[et][mt][1]),
                                               acc[hh][dt][et], 0, 0, 0);
        }
    }

    // A3. coalesced xnT write (after compute; stores drain in other blocks' shadow)
    char* dst = (char*)xnT + ((size_t)batch * NPOS + pb) * 128;
#pragma unroll
    for (int i = 0; i < 8; ++i) {
        int u = i * 256 + tid;
        int r = u >> 3, cl = u & 7;
        u32x4 w = *(const u32x4*)(xnz + r * 128 + ((cl ^ (r & 7)) << 4));
        *(u32x4*)(dst + (size_t)u * 16) = w;
    }

    // C. combine
    __syncthreads();
#pragma unroll
    for (int hh = 0; hh < 2; ++hh) {
#pragma unroll
        for (int dt = 0; dt < 2; ++dt) {
#pragma unroll
            for (int et = 0; et < 2; ++et)
#pragma unroll
                for (int r4 = 0; r4 < 4; ++r4)
                    lctx[wid][hh][dt * 16 + g * 4 + r4][et * 16 + m] = acc[hh][dt][et][r4];
            float z = zacc[hh][dt];
            z += __shfl_xor(z, 16);
            z += __shfl_xor(z, 32);
            if (g == 0) lz[wid][hh][dt * 16 + m] = z;
        }
    }
    __syncthreads();

    float* P = partials + (size_t)blk * 4224;
    for (int i = tid; i < 4096; i += 256) {
        int h = i >> 10, de = i & 1023, d = de >> 5, e = de & 31;
        int w0 = h >> 1, hh2 = h & 1;
        P[i] = lctx[w0][hh2][d][e] + lctx[w0 + 2][hh2][d][e];
    }
    if (tid < 128) {
        int h = tid >> 5, d = tid & 31;
        P[4096 + tid] = lz[h >> 1][h & 1][d] + lz[(h >> 1) + 2][h & 1][d];
    }
}

// ---- ctxt stage A: reduce 432 partials/batch -> 16 groups of 27 ----
__global__ __launch_bounds__(256) void la_ctxt_a(const float* __restrict__ partials,
                                                 float* __restrict__ part2)
{
    int t = blockIdx.x * 256 + threadIdx.x;       // 2*16*4224 = 135168 exactly
    int b = t / 67584;
    int rem = t % 67584;
    int grp = rem / 4224;
    int i = rem % 4224;
    const float* P = partials + ((size_t)(b * 432 + grp * 27)) * 4224 + i;
    float s = 0.f;
#pragma unroll 3
    for (int j = 0; j < 27; ++j) s += P[(size_t)j * 4224];
    part2[((size_t)(b * 16 + grp)) * 4224 + i] = s;
}

// ---- ctxt stage B: one block per (b,h): final sum + mem_kv fold + W2 = wout.ctx^T
//      (folds pass2's third GEMM into an 8KB precomputed bf16 matrix). ----
__global__ __launch_bounds__(256) void la_ctxt_b(const float* __restrict__ part2,
                                                 const float* __restrict__ mem_kv,
                                                 const float* __restrict__ wout_f,
                                                 short* __restrict__ W2bf)
{
    __shared__ float ctxN[32][33];
    const int tid = threadIdx.x;
    const int b = blockIdx.x >> 2, h = blockIdx.x & 3;
    const float* P = part2 + (size_t)b * 16 * 4224;
#pragma unroll
    for (int u = 0; u < 4; ++u) {
        int de = tid * 4 + u;
        int d = de >> 5, e = de & 31;
        float S = 0.f, Z = 0.f;
#pragma unroll 4
        for (int grp = 0; grp < 16; ++grp) {
            S += P[(size_t)grp * 4224 + h * 1024 + de];
            Z += P[(size_t)grp * 4224 + 4096 + h * 32 + d];
        }
        const float* mk = mem_kv + (h * 32 + d) * 4;
        const float* mv = mem_kv + 512 + (h * 32 + e) * 4;
#pragma unroll
        for (int mm = 0; mm < 4; ++mm) {
            float ekv = __expf(mk[mm]);
            S += ekv * mv[mm];
            Z += ekv;
        }
        ctxN[d][e] = S / Z;
    }
    __syncthreads();
    // W2[c][h*32+d] = sum_e wout[c][h*32+e] * ctx_h[d][e]   (f32, one bf16 rounding)
#pragma unroll
    for (int u = 0; u < 8; ++u) {
        int idx = u * 256 + tid;          // 0..2047
        int c = idx >> 5, d = idx & 31;
        const float* wr = wout_f + c * 128 + h * 32;
        float s = 0.f;
#pragma unroll
        for (int e = 0; e < 32; ++e) s += wr[e] * ctxN[d][e];
        W2bf[(size_t)(b * 64 + c) * 128 + h * 32 + d] = f2bf(s);
    }
}

// ---- pass2: EQ GEMM -> exp -> normalize -> single W2 GEMM (K=128) -> rmsnorm.
//      Third GEMM folded into W2; 192->128 MFMA, one pipeline stage removed. ----
__global__ __launch_bounds__(256, 2) void la_pass2(
    const short* __restrict__ xnT, const short* __restrict__ wq,
    const short* __restrict__ W2, const float* __restrict__ b_out,
    const float* __restrict__ g_out, float* __restrict__ out)
{
    const int tid = threadIdx.x, lane = tid & 63, wid = tid >> 6;
    const int g = lane >> 4, m = lane & 15;
    const int blk = blockIdx.x;
    const int batch = blk / 432;
    const int task = (blk % 432) * 4 + wid;   // [0, 1728): 64-pos tasks per batch
    const int posbase = task * 64;

    const short* xp = xnT + ((size_t)batch * NPOS + posbase) * 64;
    bf16x8 af[4][2];
#pragma unroll
    for (int mt = 0; mt < 4; ++mt)
#pragma unroll
        for (int kf = 0; kf < 2; ++kf)
            af[mt][kf] = *(const bf16x8*)(xp + (mt * 16 + m) * 64 + kf * 32 + g * 8);

    f32x4 oacc[4][4];   // [ct][mt]
#pragma unroll
    for (int ct = 0; ct < 4; ++ct)
#pragma unroll
        for (int mt = 0; mt < 4; ++mt) oacc[ct][mt] = (f32x4){0.f, 0.f, 0.f, 0.f};

    const float scale = 0.17677669529663687f;   // 32^-0.5
    const short* w2b = W2 + (size_t)batch * 8192;

#pragma unroll 1
    for (int h = 0; h < 4; ++h) {
        // EQ = exp(Wq . Xn^T): C[d][p], d on (g,r), p on m
        f32x4 aa[2][4];     // [dt][mt], static
#pragma unroll
        for (int dt = 0; dt < 2; ++dt) {
            const short* wr = wq + (size_t)(h * 32 + dt * 16 + m) * 64 + g * 8;
            bf16x8 a0 = *(const bf16x8*)wr;
            bf16x8 a1 = *(const bf16x8*)(wr + 32);
#pragma unroll
            for (int mt = 0; mt < 4; ++mt) {
                f32x4 a = {0.f, 0.f, 0.f, 0.f};
                a = MFMA(a0, af[mt][0], a, 0, 0, 0);
                a = MFMA(a1, af[mt][1], a, 0, 0, 0);
                aa[dt][mt][0] = __expf(a[0]);
                aa[dt][mt][1] = __expf(a[1]);
                aa[dt][mt][2] = __expf(a[2]);
                aa[dt][mt][3] = __expf(a[3]);
            }
        }
        float inv[4];
#pragma unroll
        for (int mt = 0; mt < 4; ++mt) {
            float dn = (aa[0][mt][0] + aa[0][mt][1]) + (aa[0][mt][2] + aa[0][mt][3])
                     + (aa[1][mt][0] + aa[1][mt][1]) + (aa[1][mt][2] + aa[1][mt][3]);
            dn += __shfl_xor(dn, 16);
            dn += __shfl_xor(dn, 32);
            inv[mt] = scale / dn;
        }
        // normalized EQ pack (C-layout rows d, cols p)
        u32 eqn[2][4][2];   // [dt][mt][q]
#pragma unroll
        for (int dt = 0; dt < 2; ++dt)
#pragma unroll
            for (int mt = 0; mt < 4; ++mt) {
                eqn[dt][mt][0] = pack2(aa[dt][mt][0] * inv[mt], aa[dt][mt][1] * inv[mt]);
                eqn[dt][mt][1] = pack2(aa[dt][mt][2] * inv[mt], aa[dt][mt][3] * inv[mt]);
            }
        // out[c][p] += sum_d W2[c][h*32+d] * EQn[d][p]  (contract d = C-row of EQ)
#pragma unroll
        for (int ct = 0; ct < 4; ++ct)
#pragma unroll
            for (int dt = 0; dt < 2; ++dt) {
                u32x2 wv = *(const u32x2*)(w2b + (ct * 16 + m) * 128 + h * 32 + dt * 16 + g * 4);
                bf16x8 wfr = padfrag(wv.x, wv.y);
#pragma unroll
                for (int mt = 0; mt < 4; ++mt)
                    oacc[ct][mt] = MFMA(wfr, padfrag(eqn[dt][mt][0], eqn[dt][mt][1]),
                                        oacc[ct][mt], 0, 0, 0);
            }
    }

    // epilogue: +b_out, rmsnorm over c, *g_out, store (c = ct*16+g*4+r, p = posbase+mt*16+m)
    float bo[4][4], go[4][4];
#pragma unroll
    for (int ct = 0; ct < 4; ++ct)
#pragma unroll
        for (int r = 0; r < 4; ++r) {
            int c = ct * 16 + g * 4 + r;
            bo[ct][r] = b_out[c];
            go[ct][r] = g_out[c];
        }
    float* ob = out + (size_t)batch * 64 * NPOS;
#pragma unroll
    for (int mt = 0; mt < 4; ++mt) {
        float vv[4][4]; float s2 = 0.f;
#pragma unroll
        for (int ct = 0; ct < 4; ++ct)
#pragma unroll
            for (int r = 0; r < 4; ++r) {
                float v = oacc[ct][mt][r] + bo[ct][r];
                vv[ct][r] = v;
                s2 += v * v;
            }
        s2 += __shfl_xor(s2, 16);
        s2 += __shfl_xor(s2, 32);
        float rn2 = 8.0f / fmaxf(sqrtf(s2), 1e-12f);
        int pn = posbase + mt * 16 + m;
#pragma unroll
        for (int ct = 0; ct < 4; ++ct)
#pragma unroll
            for (int r = 0; r < 4; ++r)
                ob[(size_t)(ct * 16 + g * 4 + r) * NPOS + pn] = vv[ct][r] * rn2 * go[ct][r];
    }
}

extern "C" void kernel_launch(void* const* d_in, const int* in_sizes, int n_in,
                              void* d_out, int out_size, void* d_ws, size_t ws_size,
                              hipStream_t stream) {
    const float* x      = (const float*)d_in[0];
    const float* g_in   = (const float*)d_in[1];
    const float* w_qkv  = (const float*)d_in[2];
    const float* mem_kv = (const float*)d_in[3];
    const float* w_out  = (const float*)d_in[4];
    const float* b_out  = (const float*)d_in[5];
    const float* g_out  = (const float*)d_in[6];
    float* out = (float*)d_out;

    char* ws = (char*)d_ws;
    short* xnT     = (short*)(ws);                 // 28,311,552 B
    float* part2   = (float*)(ws + 28311552);      //    540,672 B (2*16*4224 f32)
    short* wqkv_bf = (short*)(ws + 28852224);      //     49,152 B
    short* W2bf    = (short*)(ws + 28901376);      //     32,768 B (2*64*128 bf16)

    // p01 partials (864*4224 f32 = 14.6 MB) live in d_out scratch; fully consumed
    // by la_ctxt_a before la_pass2 overwrites d_out with the real output.
    float* partials = (float*)d_out;

    la_prep<<<96, 256, 0, stream>>>(w_qkv, g_in, wqkv_bf);
    la_p01<<<864, 256, 0, stream>>>(x, wqkv_bf, xnT, partials);
    la_ctxt_a<<<528, 256, 0, stream>>>(partials, part2);
    la_ctxt_b<<<8, 256, 0, stream>>>(part2, mem_kv, w_out, W2bf);
    la_pass2<<<864, 256, 0, stream>>>(xnT, wqkv_bf, W2bf, b_out, g_out, out);
}

// Round 12
// 97.562 us; speedup vs baseline: 1.1303x; 1.0047x over previous
//
#include <hip/hip_runtime.h>
#include <hip/hip_cooperative_groups.h>
#include <math.h>

namespace cg = cooperative_groups;

#define NPOS 110592

typedef float f32x4 __attribute__((ext_vector_type(4)));
typedef short bf16x8 __attribute__((ext_vector_type(8)));
typedef unsigned u32;
typedef u32 u32x2 __attribute__((ext_vector_type(2)));
typedef u32 u32x4 __attribute__((ext_vector_type(4)));

#define MFMA __builtin_amdgcn_mfma_f32_16x16x32_bf16

__device__ __forceinline__ short f2bf(float f) {
    u32 u = __builtin_bit_cast(u32, f);
    u += 0x7fffu + ((u >> 16) & 1u);
    return (short)(u >> 16);
}
// ALU round-to-nearest-even pack (proven rounds 1-11).
__device__ __forceinline__ u32 pack2(float a, float b) {
    return (u32)(unsigned short)f2bf(a) | ((u32)(unsigned short)f2bf(b) << 16);
}

union FragU { u32 w[4]; bf16x8 v; };
// C-layout regs (k on slots g*8+{0,1,2,3}) -> K-padded fragment, slots 4..7 = 0.
__device__ __forceinline__ bf16x8 padfrag(u32 a, u32 b) {
    FragU f; f.w[0] = a; f.w[1] = b; f.w[2] = 0u; f.w[3] = 0u; return f.v;
}

// ---- prep: bf16 qkv weights, g_in folded into columns ----
__global__ __launch_bounds__(256) void la_prep(const float* __restrict__ wqkv,
                                               const float* __restrict__ g_in,
                                               short* __restrict__ wqkv_bf)
{
    int i = blockIdx.x * 256 + threadIdx.x;
    if (i < 24576) wqkv_bf[i] = f2bf(wqkv[i] * g_in[i & 63]);
}

// =================== cooperative fused kernel ===================
// LDS: xnz 32768 + lctx 4224 + lz 128 = 37120 B -> 4 blocks/CU -> 1024 >= 864
// co-resident (launch_bounds(256,4) caps VGPR at 128).
__global__ __launch_bounds__(256, 4) void la_fused(
    const float* __restrict__ x, const short* __restrict__ wqkv,
    const float* __restrict__ mem_kv, const float* __restrict__ wout_f,
    const float* __restrict__ b_out, const float* __restrict__ g_out,
    float* __restrict__ partials, float* __restrict__ ctxG,
    short* __restrict__ W2bf, float* __restrict__ out)
{
    __shared__ __align__(16) char xnz[32768];
    __shared__ float lctx[32][33];
    __shared__ float lz[32];

    const int tid = threadIdx.x, lane = tid & 63, wid = tid >> 6;
    const int g = lane >> 4, m = lane & 15;
    const int blk = blockIdx.x;
    const int batch = blk / 432;
    const int pb = (blk % 432) * 256;

    // ---- Phase A: coalesced x read + rmsnorm + swizzled LDS stage (r11 verbatim) ----
    {
        const float* base = x + (size_t)batch * 64 * NPOS + pb + tid;
        float xv[64]; float ss = 0.f;
#pragma unroll
        for (int c = 0; c < 64; ++c) { float t = base[(size_t)c * NPOS]; xv[c] = t; ss += t * t; }
        float rn = 8.0f / fmaxf(sqrtf(ss), 1e-12f);
        char* row = xnz + tid * 128;
#pragma unroll
        for (int ch = 0; ch < 8; ++ch) {
            u32x4 w;
            w.x = pack2(xv[ch*8+0] * rn, xv[ch*8+1] * rn);
            w.y = pack2(xv[ch*8+2] * rn, xv[ch*8+3] * rn);
            w.z = pack2(xv[ch*8+4] * rn, xv[ch*8+5] * rn);
            w.w = pack2(xv[ch*8+6] * rn, xv[ch*8+7] * rn);
            *(u32x4*)(row + ((ch ^ (tid & 7)) << 4)) = w;
        }
    }
    __syncthreads();

    // ---- Phase B: ctx partials (wave = 128 pos x 2 heads; r8-proven per-use loads) ----
    const int cgrp = wid >> 1, hbase = (wid & 1) * 2;
    f32x4 acc[2][2][2];
#pragma unroll
    for (int hh = 0; hh < 2; ++hh)
#pragma unroll
        for (int dt = 0; dt < 2; ++dt)
#pragma unroll
            for (int et = 0; et < 2; ++et) acc[hh][dt][et] = (f32x4){0.f, 0.f, 0.f, 0.f};
    float zacc[2][2] = {{0.f, 0.f}, {0.f, 0.f}};

#pragma unroll 1
    for (int ic = 0; ic < 4; ++ic) {
        bf16x8 af[2][2];
#pragma unroll
        for (int mt = 0; mt < 2; ++mt)
#pragma unroll
            for (int kf = 0; kf < 2; ++kf) {
                int rowi = cgrp * 128 + ic * 32 + mt * 16 + m;
                af[mt][kf] = *(const bf16x8*)(xnz + rowi * 128 + (((kf*4+g) ^ (rowi & 7)) << 4));
            }
#pragma unroll
        for (int hh = 0; hh < 2; ++hh) {
            const int h = hbase + hh;
            u32 ek[2][2][2], vv[2][2][2];
#pragma unroll
            for (int dt = 0; dt < 2; ++dt) {
                const short* wr = wqkv + (size_t)(128 + h * 32 + dt * 16 + m) * 64 + g * 8;
                bf16x8 w0 = *(const bf16x8*)wr;
                bf16x8 w1 = *(const bf16x8*)(wr + 32);
#pragma unroll
                for (int mt = 0; mt < 2; ++mt) {
                    f32x4 a = {0.f, 0.f, 0.f, 0.f};
                    a = MFMA(af[mt][0], w0, a, 0, 0, 0);
                    a = MFMA(af[mt][1], w1, a, 0, 0, 0);
                    float e0 = __expf(a[0]), e1 = __expf(a[1]);
                    float e2 = __expf(a[2]), e3 = __expf(a[3]);
                    zacc[hh][dt] += (e0 + e1) + (e2 + e3);
                    ek[dt][mt][0] = pack2(e0, e1);
                    ek[dt][mt][1] = pack2(e2, e3);
                }
            }
#pragma unroll
            for (int et = 0; et < 2; ++et) {
                const short* wr = wqkv + (size_t)(256 + h * 32 + et * 16 + m) * 64 + g * 8;
                bf16x8 w0 = *(const bf16x8*)wr;
                bf16x8 w1 = *(const bf16x8*)(wr + 32);
#pragma unroll
                for (int mt = 0; mt < 2; ++mt) {
                    f32x4 a = {0.f, 0.f, 0.f, 0.f};
                    a = MFMA(af[mt][0], w0, a, 0, 0, 0);
                    a = MFMA(af[mt][1], w1, a, 0, 0, 0);
                    vv[et][mt][0] = pack2(a[0], a[1]);
                    vv[et][mt][1] = pack2(a[2], a[3]);
                }
            }
#pragma unroll
            for (int dt = 0; dt < 2; ++dt)
#pragma unroll
                for (int et = 0; et < 2; ++et)
#pragma unroll
                    for (int mt = 0; mt < 2; ++mt)
                        acc[hh][dt][et] = MFMA(padfrag(ek[dt][mt][0], ek[dt][mt][1]),
                                               padfrag(vv[et][mt][0], vv[et][mt][1]),
                                               acc[hh][dt][et], 0, 0, 0);
        }
    }

    // ---- Combine: 8 static rounds through 4.2KB lctx, register accumulation.
    // Round r=(w,hh): head H=(w&1)*2+hh; each head H gets waves {H>>1, (H>>1)+2}
    // (same mapping as r11's lctx[w0][hh2] + lctx[w0+2][hh2]). All indices static.
    float ctxsum[4][4];
#pragma unroll
    for (int H = 0; H < 4; ++H)
#pragma unroll
        for (int k = 0; k < 4; ++k) ctxsum[H][k] = 0.f;
    float zsum = 0.f;

#pragma unroll
    for (int r = 0; r < 8; ++r) {
        const int w = r >> 1, hh = r & 1;
        const int H = (w & 1) * 2 + hh;
        if (wid == w) {
#pragma unroll
            for (int dt = 0; dt < 2; ++dt) {
#pragma unroll
                for (int et = 0; et < 2; ++et)
#pragma unroll
                    for (int r4 = 0; r4 < 4; ++r4)
                        lctx[dt * 16 + g * 4 + r4][et * 16 + m] = acc[hh][dt][et][r4];
                float z = zacc[hh][dt];
                z += __shfl_xor(z, 16);
                z += __shfl_xor(z, 32);
                if (g == 0) lz[dt * 16 + m] = z;
            }
        }
        __syncthreads();
#pragma unroll
        for (int k = 0; k < 4; ++k) {
            int cell = tid * 4 + k;
            ctxsum[H][k] += lctx[cell >> 5][cell & 31];
        }
        if ((tid >> 5) == H) zsum += lz[tid & 31];
        __syncthreads();
    }
    {
        float* P = partials + (size_t)blk * 4224;
#pragma unroll
        for (int H = 0; H < 4; ++H) {
            f32x4 v;
            v[0] = ctxsum[H][0]; v[1] = ctxsum[H][1];
            v[2] = ctxsum[H][2]; v[3] = ctxsum[H][3];
            *(f32x4*)(P + H * 1024 + tid * 4) = v;
        }
        if (tid < 128) P[4096 + tid] = zsum;
    }

    cg::this_grid().sync();

    // ---- Phase C: 132 blocks reduce 864 partials (108-deep x 4 quarters, atomic) ----
    if (blk < 132) {
        int t = blk * 256 + tid;            // < 33792 = 4 * 8448
        int q = t / 8448;
        int u = t % 8448;
        int b = u / 4224, i = u % 4224;
        const float* Q = partials + ((size_t)(b * 432 + q * 108)) * 4224 + i;
        float s = 0.f;
#pragma unroll 8
        for (int j = 0; j < 108; ++j) s += Q[(size_t)j * 4224];
        atomicAdd(&ctxG[b * 4224 + i], s);
    }
    cg::this_grid().sync();

    // ---- Phase C2: 8 blocks (b,h): mem_kv fold + W2 = wout . ctx^T ----
    if (blk < 8) {
        float (*ctxN)[33] = lctx;          // reuse lctx region (free now)
        const int b = blk >> 2, h = blk & 3;
#pragma unroll
        for (int u = 0; u < 4; ++u) {
            int de = tid * 4 + u;
            int d = de >> 5, e = de & 31;
            float S = ctxG[b * 4224 + h * 1024 + de];
            float Z = ctxG[b * 4224 + 4096 + h * 32 + d];
            const float* mk = mem_kv + (h * 32 + d) * 4;
            const float* mv = mem_kv + 512 + (h * 32 + e) * 4;
#pragma unroll
            for (int mm = 0; mm < 4; ++mm) {
                float ekv = __expf(mk[mm]);
                S += ekv * mv[mm];
                Z += ekv;
            }
            ctxN[d][e] = S / Z;
        }
        __syncthreads();
#pragma unroll
        for (int u = 0; u < 8; ++u) {
            int idx = u * 256 + tid;        // 0..2047
            int c = idx >> 5, d = idx & 31;
            const float* wr = wout_f + c * 128 + h * 32;
            float s = 0.f;
#pragma unroll
            for (int e = 0; e < 32; ++e) s += wr[e] * ctxN[d][e];
            W2bf[(size_t)(b * 64 + c) * 128 + h * 32 + d] = f2bf(s);
        }
    }
    cg::this_grid().sync();

    // ---- Phase D: pass2 with xn still in LDS; two 32-pos halves per wave ----
    const short* w2b = W2bf + (size_t)batch * 8192;
    const float scale = 0.17677669529663687f;   // 32^-0.5
    float* ob = out + (size_t)batch * 64 * NPOS;

#pragma unroll 1
    for (int half = 0; half < 2; ++half) {
        bf16x8 af[2][2];
#pragma unroll
        for (int mt = 0; mt < 2; ++mt)
#pragma unroll
            for (int kf = 0; kf < 2; ++kf) {
                int rowi = wid * 64 + half * 32 + mt * 16 + m;
                af[mt][kf] = *(const bf16x8*)(xnz + rowi * 128 + (((kf*4+g) ^ (rowi & 7)) << 4));
            }
        f32x4 oacc[4][2];
#pragma unroll
        for (int ct = 0; ct < 4; ++ct)
#pragma unroll
            for (int mt = 0; mt < 2; ++mt) oacc[ct][mt] = (f32x4){0.f, 0.f, 0.f, 0.f};

#pragma unroll 1
        for (int h = 0; h < 4; ++h) {
            f32x4 aa[2][2];
#pragma unroll
            for (int dt = 0; dt < 2; ++dt) {
                const short* wr = wqkv + (size_t)(h * 32 + dt * 16 + m) * 64 + g * 8;
                bf16x8 a0 = *(const bf16x8*)wr;
                bf16x8 a1 = *(const bf16x8*)(wr + 32);
#pragma unroll
                for (int mt = 0; mt < 2; ++mt) {
                    f32x4 a = {0.f, 0.f, 0.f, 0.f};
                    a = MFMA(a0, af[mt][0], a, 0, 0, 0);
                    a = MFMA(a1, af[mt][1], a, 0, 0, 0);
                    aa[dt][mt][0] = __expf(a[0]);
                    aa[dt][mt][1] = __expf(a[1]);
                    aa[dt][mt][2] = __expf(a[2]);
                    aa[dt][mt][3] = __expf(a[3]);
                }
            }
            float inv[2];
#pragma unroll
            for (int mt = 0; mt < 2; ++mt) {
                float dn = (aa[0][mt][0] + aa[0][mt][1]) + (aa[0][mt][2] + aa[0][mt][3])
                         + (aa[1][mt][0] + aa[1][mt][1]) + (aa[1][mt][2] + aa[1][mt][3]);
                dn += __shfl_xor(dn, 16);
                dn += __shfl_xor(dn, 32);
                inv[mt] = scale / dn;
            }
            u32 eqn[2][2][2];
#pragma unroll
            for (int dt = 0; dt < 2; ++dt)
#pragma unroll
                for (int mt = 0; mt < 2; ++mt) {
                    eqn[dt][mt][0] = pack2(aa[dt][mt][0] * inv[mt], aa[dt][mt][1] * inv[mt]);
                    eqn[dt][mt][1] = pack2(aa[dt][mt][2] * inv[mt], aa[dt][mt][3] * inv[mt]);
                }
#pragma unroll
            for (int ct = 0; ct < 4; ++ct)
#pragma unroll
                for (int dt = 0; dt < 2; ++dt) {
                    u32x2 wv = *(const u32x2*)(w2b + (ct * 16 + m) * 128 + h * 32 + dt * 16 + g * 4);
                    bf16x8 wfr = padfrag(wv.x, wv.y);
#pragma unroll
                    for (int mt = 0; mt < 2; ++mt)
                        oacc[ct][mt] = MFMA(wfr, padfrag(eqn[dt][mt][0], eqn[dt][mt][1]),
                                            oacc[ct][mt], 0, 0, 0);
                }
        }

        // epilogue for this half
#pragma unroll
        for (int mt = 0; mt < 2; ++mt) {
            float vv[4][4]; float s2 = 0.f;
#pragma unroll
            for (int ct = 0; ct < 4; ++ct)
#pragma unroll
                for (int r = 0; r < 4; ++r) {
                    float v = oacc[ct][mt][r] + b_out[ct * 16 + g * 4 + r];
                    vv[ct][r] = v;
                    s2 += v * v;
                }
            s2 += __shfl_xor(s2, 16);
            s2 += __shfl_xor(s2, 32);
            float rn2 = 8.0f / fmaxf(sqrtf(s2), 1e-12f);
            int pn = pb + wid * 64 + half * 32 + mt * 16 + m;
#pragma unroll
            for (int ct = 0; ct < 4; ++ct)
#pragma unroll
                for (int r = 0; r < 4; ++r)
                    ob[(size_t)(ct * 16 + g * 4 + r) * NPOS + pn] =
                        vv[ct][r] * rn2 * g_out[ct * 16 + g * 4 + r];
        }
    }
}

// =================== fallback: round-11 proven pipeline ===================
__global__ __launch_bounds__(256, 3) void la_p01(
    const float* __restrict__ x, const short* __restrict__ wkv,
    short* __restrict__ xnT, float* __restrict__ partials)
{
    __shared__ __align__(16) char smem[34816];
    char* xnz = smem;
    float (*lctx)[2][32][33] = (float (*)[2][32][33])smem;
    float (*lz)[2][32]       = (float (*)[2][32])(smem + 33792);

    const int tid = threadIdx.x, lane = tid & 63, wid = tid >> 6;
    const int g = lane >> 4, m = lane & 15;
    const int blk = blockIdx.x;
    const int batch = blk / 432;
    const int pb = (blk % 432) * 256;

    const float* base = x + (size_t)batch * 64 * NPOS + pb + tid;
    float xv[64]; float ss = 0.f;
#pragma unroll
    for (int c = 0; c < 64; ++c) { float t = base[(size_t)c * NPOS]; xv[c] = t; ss += t * t; }
    float rn = 8.0f / fmaxf(sqrtf(ss), 1e-12f);
    char* row = xnz + tid * 128;
#pragma unroll
    for (int ch = 0; ch < 8; ++ch) {
        u32x4 w;
        w.x = pack2(xv[ch*8+0] * rn, xv[ch*8+1] * rn);
        w.y = pack2(xv[ch*8+2] * rn, xv[ch*8+3] * rn);
        w.z = pack2(xv[ch*8+4] * rn, xv[ch*8+5] * rn);
        w.w = pack2(xv[ch*8+6] * rn, xv[ch*8+7] * rn);
        *(u32x4*)(row + ((ch ^ (tid & 7)) << 4)) = w;
    }
    __syncthreads();

    const int cgrp = wid >> 1, hbase = (wid & 1) * 2;
    bf16x8 wkA[2][2][2], wvA[2][2][2];
#pragma unroll
    for (int hh = 0; hh < 2; ++hh) {
#pragma unroll
        for (int dt = 0; dt < 2; ++dt) {
            const short* wr = wkv + (size_t)(128 + (hbase + hh) * 32 + dt * 16 + m) * 64 + g * 8;
            wkA[hh][dt][0] = *(const bf16x8*)wr;
            wkA[hh][dt][1] = *(const bf16x8*)(wr + 32);
        }
#pragma unroll
        for (int et = 0; et < 2; ++et) {
            const short* wr = wkv + (size_t)(256 + (hbase + hh) * 32 + et * 16 + m) * 64 + g * 8;
            wvA[hh][et][0] = *(const bf16x8*)wr;
            wvA[hh][et][1] = *(const bf16x8*)(wr + 32);
        }
    }
    f32x4 acc[2][2][2];
#pragma unroll
    for (int hh = 0; hh < 2; ++hh)
#pragma unroll
        for (int dt = 0; dt < 2; ++dt)
#pragma unroll
            for (int et = 0; et < 2; ++et) acc[hh][dt][et] = (f32x4){0.f, 0.f, 0.f, 0.f};
    float zacc[2][2] = {{0.f, 0.f}, {0.f, 0.f}};

#pragma unroll 1
    for (int ic = 0; ic < 4; ++ic) {
        bf16x8 af[2][2];
#pragma unroll
        for (int mt = 0; mt < 2; ++mt)
#pragma unroll
            for (int kf = 0; kf < 2; ++kf) {
                int rowi = cgrp * 128 + ic * 32 + mt * 16 + m;
                af[mt][kf] = *(const bf16x8*)(xnz + rowi * 128 + (((kf*4+g) ^ (rowi & 7)) << 4));
            }
#pragma unroll
        for (int hh = 0; hh < 2; ++hh) {
            u32 ek[2][2][2], vv[2][2][2];
#pragma unroll
            for (int dt = 0; dt < 2; ++dt)
#pragma unroll
                for (int mt = 0; mt < 2; ++mt) {
                    f32x4 a = {0.f, 0.f, 0.f, 0.f};
                    a = MFMA(af[mt][0], wkA[hh][dt][0], a, 0, 0, 0);
                    a = MFMA(af[mt][1], wkA[hh][dt][1], a, 0, 0, 0);
                    float e0 = __expf(a[0]), e1 = __expf(a[1]);
                    float e2 = __expf(a[2]), e3 = __expf(a[3]);
                    zacc[hh][dt] += (e0 + e1) + (e2 + e3);
                    ek[dt][mt][0] = pack2(e0, e1);
                    ek[dt][mt][1] = pack2(e2, e3);
                }
#pragma unroll
            for (int et = 0; et < 2; ++et)
#pragma unroll
                for (int mt = 0; mt < 2; ++mt) {
                    f32x4 a = {0.f, 0.f, 0.f, 0.f};
                    a = MFMA(af[mt][0], wvA[hh][et][0], a, 0, 0, 0);
                    a = MFMA(af[mt][1], wvA[hh][et][1], a, 0, 0, 0);
                    vv[et][mt][0] = pack2(a[0], a[1]);
                    vv[et][mt][1] = pack2(a[2], a[3]);
                }
#pragma unroll
            for (int dt = 0; dt < 2; ++dt)
#pragma unroll
                for (int et = 0; et < 2; ++et)
#pragma unroll
                    for (int mt = 0; mt < 2; ++mt)
                        acc[hh][dt][et] = MFMA(padfrag(ek[dt][mt][0], ek[dt][mt][1]),
                                               padfrag(vv[et][mt][0], vv[et][mt][1]),
                                               acc[hh][dt][et], 0, 0, 0);
        }
    }

    char* dst = (char*)xnT + ((size_t)batch * NPOS + pb) * 128;
#pragma unroll
    for (int i = 0; i < 8; ++i) {
        int u = i * 256 + tid;
        int r = u >> 3, cl = u & 7;
        u32x4 w = *(const u32x4*)(xnz + r * 128 + ((cl ^ (r & 7)) << 4));
        *(u32x4*)(dst + (size_t)u * 16) = w;
    }

    __syncthreads();
#pragma unroll
    for (int hh = 0; hh < 2; ++hh)
#pragma unroll
        for (int dt = 0; dt < 2; ++dt) {
#pragma unroll
            for (int et = 0; et < 2; ++et)
#pragma unroll
                for (int r4 = 0; r4 < 4; ++r4)
                    lctx[wid][hh][dt * 16 + g * 4 + r4][et * 16 + m] = acc[hh][dt][et][r4];
            float z = zacc[hh][dt];
            z += __shfl_xor(z, 16);
            z += __shfl_xor(z, 32);
            if (g == 0) lz[wid][hh][dt * 16 + m] = z;
        }
    __syncthreads();

    float* P = partials + (size_t)blk * 4224;
    for (int i = tid; i < 4096; i += 256) {
        int h = i >> 10, de = i & 1023, d = de >> 5, e = de & 31;
        int w0 = h >> 1, hh2 = h & 1;
        P[i] = lctx[w0][hh2][d][e] + lctx[w0 + 2][hh2][d][e];
    }
    if (tid < 128) {
        int h = tid >> 5, d = tid & 31;
        P[4096 + tid] = lz[h >> 1][h & 1][d] + lz[(h >> 1) + 2][h & 1][d];
    }
}

__global__ __launch_bounds__(256) void la_ctxt_a(const float* __restrict__ partials,
                                                 float* __restrict__ part2)
{
    int t = blockIdx.x * 256 + threadIdx.x;
    int b = t / 67584;
    int rem = t % 67584;
    int grp = rem / 4224;
    int i = rem % 4224;
    const float* P = partials + ((size_t)(b * 432 + grp * 27)) * 4224 + i;
    float s = 0.f;
#pragma unroll 3
    for (int j = 0; j < 27; ++j) s += P[(size_t)j * 4224];
    part2[((size_t)(b * 16 + grp)) * 4224 + i] = s;
}

__global__ __launch_bounds__(256) void la_ctxt_b(const float* __restrict__ part2,
                                                 const float* __restrict__ mem_kv,
                                                 const float* __restrict__ wout_f,
                                                 short* __restrict__ W2bf)
{
    __shared__ float ctxN[32][33];
    const int tid = threadIdx.x;
    const int b = blockIdx.x >> 2, h = blockIdx.x & 3;
    const float* P = part2 + (size_t)b * 16 * 4224;
#pragma unroll
    for (int u = 0; u < 4; ++u) {
        int de = tid * 4 + u;
        int d = de >> 5, e = de & 31;
        float S = 0.f, Z = 0.f;
#pragma unroll 4
        for (int grp = 0; grp < 16; ++grp) {
            S += P[(size_t)grp * 4224 + h * 1024 + de];
            Z += P[(size_t)grp * 4224 + 4096 + h * 32 + d];
        }
        const float* mk = mem_kv + (h * 32 + d) * 4;
        const float* mv = mem_kv + 512 + (h * 32 + e) * 4;
#pragma unroll
        for (int mm = 0; mm < 4; ++mm) {
            float ekv = __expf(mk[mm]);
            S += ekv * mv[mm];
            Z += ekv;
        }
        ctxN[d][e] = S / Z;
    }
    __syncthreads();
#pragma unroll
    for (int u = 0; u < 8; ++u) {
        int idx = u * 256 + tid;
        int c = idx >> 5, d = idx & 31;
        const float* wr = wout_f + c * 128 + h * 32;
        float s = 0.f;
#pragma unroll
        for (int e = 0; e < 32; ++e) s += wr[e] * ctxN[d][e];
        W2bf[(size_t)(b * 64 + c) * 128 + h * 32 + d] = f2bf(s);
    }
}

__global__ __launch_bounds__(256, 2) void la_pass2(
    const short* __restrict__ xnT, const short* __restrict__ wq,
    const short* __restrict__ W2, const float* __restrict__ b_out,
    const float* __restrict__ g_out, float* __restrict__ out)
{
    const int tid = threadIdx.x, lane = tid & 63, wid = tid >> 6;
    const int g = lane >> 4, m = lane & 15;
    const int blk = blockIdx.x;
    const int batch = blk / 432;
    const int task = (blk % 432) * 4 + wid;
    const int posbase = task * 64;

    const short* xp = xnT + ((size_t)batch * NPOS + posbase) * 64;
    bf16x8 af[4][2];
#pragma unroll
    for (int mt = 0; mt < 4; ++mt)
#pragma unroll
        for (int kf = 0; kf < 2; ++kf)
            af[mt][kf] = *(const bf16x8*)(xp + (mt * 16 + m) * 64 + kf * 32 + g * 8);

    f32x4 oacc[4][4];
#pragma unroll
    for (int ct = 0; ct < 4; ++ct)
#pragma unroll
        for (int mt = 0; mt < 4; ++mt) oacc[ct][mt] = (f32x4){0.f, 0.f, 0.f, 0.f};

    const float scale = 0.17677669529663687f;
    const short* w2b = W2 + (size_t)batch * 8192;

#pragma unroll 1
    for (int h = 0; h < 4; ++h) {
        f32x4 aa[2][4];
#pragma unroll
        for (int dt = 0; dt < 2; ++dt) {
            const short* wr = wq + (size_t)(h * 32 + dt * 16 + m) * 64 + g * 8;
            bf16x8 a0 = *(const bf16x8*)wr;
            bf16x8 a1 = *(const bf16x8*)(wr + 32);
#pragma unroll
            for (int mt = 0; mt < 4; ++mt) {
                f32x4 a = {0.f, 0.f, 0.f, 0.f};
                a = MFMA(a0, af[mt][0], a, 0, 0, 0);
                a = MFMA(a1, af[mt][1], a, 0, 0, 0);
                aa[dt][mt][0] = __expf(a[0]);
                aa[dt][mt][1] = __expf(a[1]);
                aa[dt][mt][2] = __expf(a[2]);
                aa[dt][mt][3] = __expf(a[3]);
            }
        }
        float inv[4];
#pragma unroll
        for (int mt = 0; mt < 4; ++mt) {
            float dn = (aa[0][mt][0] + aa[0][mt][1]) + (aa[0][mt][2] + aa[0][mt][3])
                     + (aa[1][mt][0] + aa[1][mt][1]) + (aa[1][mt][2] + aa[1][mt][3]);
            dn += __shfl_xor(dn, 16);
            dn += __shfl_xor(dn, 32);
            inv[mt] = scale / dn;
        }
        u32 eqn[2][4][2];
#pragma unroll
        for (int dt = 0; dt < 2; ++dt)
#pragma unroll
            for (int mt = 0; mt < 4; ++mt) {
                eqn[dt][mt][0] = pack2(aa[dt][mt][0] * inv[mt], aa[dt][mt][1] * inv[mt]);
                eqn[dt][mt][1] = pack2(aa[dt][mt][2] * inv[mt], aa[dt][mt][3] * inv[mt]);
            }
#pragma unroll
        for (int ct = 0; ct < 4; ++ct)
#pragma unroll
            for (int dt = 0; dt < 2; ++dt) {
                u32x2 wv = *(const u32x2*)(w2b + (ct * 16 + m) * 128 + h * 32 + dt * 16 + g * 4);
                bf16x8 wfr = padfrag(wv.x, wv.y);
#pragma unroll
                for (int mt = 0; mt < 4; ++mt)
                    oacc[ct][mt] = MFMA(wfr, padfrag(eqn[dt][mt][0], eqn[dt][mt][1]),
                                        oacc[ct][mt], 0, 0, 0);
            }
    }

    float bo[4][4], go[4][4];
#pragma unroll
    for (int ct = 0; ct < 4; ++ct)
#pragma unroll
        for (int r = 0; r < 4; ++r) {
            int c = ct * 16 + g * 4 + r;
            bo[ct][r] = b_out[c];
            go[ct][r] = g_out[c];
        }
    float* ob = out + (size_t)batch * 64 * NPOS;
#pragma unroll
    for (int mt = 0; mt < 4; ++mt) {
        float vv[4][4]; float s2 = 0.f;
#pragma unroll
        for (int ct = 0; ct < 4; ++ct)
#pragma unroll
            for (int r = 0; r < 4; ++r) {
                float v = oacc[ct][mt][r] + bo[ct][r];
                vv[ct][r] = v;
                s2 += v * v;
            }
        s2 += __shfl_xor(s2, 16);
        s2 += __shfl_xor(s2, 32);
        float rn2 = 8.0f / fmaxf(sqrtf(s2), 1e-12f);
        int pn = posbase + mt * 16 + m;
#pragma unroll
        for (int ct = 0; ct < 4; ++ct)
#pragma unroll
            for (int r = 0; r < 4; ++r)
                ob[(size_t)(ct * 16 + g * 4 + r) * NPOS + pn] = vv[ct][r] * rn2 * go[ct][r];
    }
}

extern "C" void kernel_launch(void* const* d_in, const int* in_sizes, int n_in,
                              void* d_out, int out_size, void* d_ws, size_t ws_size,
                              hipStream_t stream) {
    const float* x      = (const float*)d_in[0];
    const float* g_in   = (const float*)d_in[1];
    const float* w_qkv  = (const float*)d_in[2];
    const float* mem_kv = (const float*)d_in[3];
    const float* w_out  = (const float*)d_in[4];
    const float* b_out  = (const float*)d_in[5];
    const float* g_out  = (const float*)d_in[6];
    float* out = (float*)d_out;

    char* ws = (char*)d_ws;
    // cooperative-path layout
    float* partials = (float*)ws;                  // 864*4224*4 = 14,598,144 B
    float* ctxG     = (float*)(ws + 14598144);     //     33,792 B
    short* wqkv_bf  = (short*)(ws + 14631936);     //     49,152 B
    short* W2bf     = (short*)(ws + 14681088);     //     32,768 B

    int nb = 0;
    hipError_t qe = hipOccupancyMaxActiveBlocksPerMultiprocessor(
        &nb, reinterpret_cast<const void*>(la_fused), 256, 0);
    if (qe == hipSuccess && nb >= 4) {
        la_prep<<<96, 256, 0, stream>>>(w_qkv, g_in, wqkv_bf);
        hipMemsetAsync(ctxG, 0, 33792, stream);
        const float* xa = x; const short* wa = wqkv_bf;
        const float* ma = mem_kv; const float* wo = w_out;
        const float* ba = b_out; const float* ga = g_out;
        float* pa = partials; float* ca = ctxG; short* w2a = W2bf; float* oa = out;
        void* args[] = {(void*)&xa, (void*)&wa, (void*)&ma, (void*)&wo, (void*)&ba,
                        (void*)&ga, (void*)&pa, (void*)&ca, (void*)&w2a, (void*)&oa};
        hipError_t e = hipLaunchCooperativeKernel(
            reinterpret_cast<const void*>(la_fused), dim3(864), dim3(256), args, 0, stream);
        if (e == hipSuccess) return;
        (void)hipGetLastError();   // clear, fall through to proven pipeline
    }

    // fallback: round-11 proven pipeline (own ws layout; paths mutually exclusive)
    short* xnT      = (short*)ws;                  // 28,311,552 B
    float* part2    = (float*)(ws + 28311552);     //    540,672 B
    short* wqkv_bf2 = (short*)(ws + 28852224);     //     49,152 B
    short* W2bf2    = (short*)(ws + 28901376);     //     32,768 B
    float* partialsF = (float*)d_out;              // consumed before pass2 writes out

    la_prep<<<96, 256, 0, stream>>>(w_qkv, g_in, wqkv_bf2);
    la_p01<<<864, 256, 0, stream>>>(x, wqkv_bf2, xnT, partialsF);
    la_ctxt_a<<<528, 256, 0, stream>>>(partialsF, part2);
    la_ctxt_b<<<8, 256, 0, stream>>>(part2, mem_kv, w_out, W2bf2);
    la_pass2<<<864, 256, 0, stream>>>(xnT, wqkv_bf2, W2bf2, b_out, g_out, out);
}